// Round 1
// baseline (29.224 us; speedup 1.0000x reference)
//
#include <hip/hip_runtime.h>
#include <math.h>

#define BB 2
#define LL 1024
#define DD 256
#define UU 32
#define JW 128   // band width: j in [i-64, i+63]

__device__ __forceinline__ float fast_tanh(float x) {
    // tanh(x) = (e^{2x}-1)/(e^{2x}+1); clamp so exp never overflows
    x = fminf(10.0f, fmaxf(-10.0f, x));
    float t = __expf(2.0f * x);
    return (t - 1.0f) / (t + 1.0f);
}

// q[row,u] = x[row,:] . Wt[:,u];  k[row,u] = x[row,:] . Wx[:,u] + bh[u]
// 8 rows per block, 32 units per row group.
__global__ __launch_bounds__(256) void qk_kernel(
    const float* __restrict__ x, const float* __restrict__ Wt,
    const float* __restrict__ Wx, const float* __restrict__ bh,
    float* __restrict__ q, float* __restrict__ k)
{
    int tid = threadIdx.x;
    int u = tid & 31;
    int r = tid >> 5;
    int row = blockIdx.x * 8 + r;           // 0 .. B*L-1
    const float* xr = x + (size_t)row * DD;
    float accq = 0.0f;
    float acck = bh[u];
    #pragma unroll 4
    for (int d = 0; d < DD; ++d) {
        float xv = xr[d];
        accq = fmaf(xv, Wt[d * UU + u], accq);
        acck = fmaf(xv, Wx[d * UU + u], acck);
    }
    q[(size_t)row * UU + u] = accq;
    k[(size_t)row * UU + u] = acck;
}

// One block per output row (b,i). 256 threads.
__global__ __launch_bounds__(256) void attn_kernel(
    const float* __restrict__ x, const float* __restrict__ q,
    const float* __restrict__ k, const float* __restrict__ Wa,
    const float* __restrict__ ba, float* __restrict__ out)
{
    __shared__ float s_q[UU];
    __shared__ float s_e[JW];
    __shared__ float s_a[JW];
    __shared__ float s_sum;

    int t = threadIdx.x;
    int row = blockIdx.x;        // b*L + i
    int i = row & (LL - 1);
    int base = row - i;          // b*L

    if (t < UU) s_q[t] = q[(size_t)row * UU + t];
    __syncthreads();

    int jlo = max(0, i - 64);
    int jhi = min(LL - 1, i + 63);
    int nj = jhi - jlo + 1;

    // Phase 1: e_j = exp(Wa . tanh(q_i + k_j) + ba) for each band position
    if (t < JW) {
        float e = 0.0f;
        if (t < nj) {
            const float* kj = k + (size_t)(base + jlo + t) * UU;
            float acc = ba[0];
            #pragma unroll
            for (int u = 0; u < UU; ++u)
                acc = fmaf(Wa[u], fast_tanh(s_q[u] + kj[u]), acc);
            e = __expf(acc);
        }
        s_e[t] = e;
    }
    __syncthreads();

    // Phase 2: sum over 128 band entries -> softmax weights
    if (t < 64) {
        float v = s_e[t] + s_e[t + 64];
        #pragma unroll
        for (int off = 32; off > 0; off >>= 1)
            v += __shfl_down(v, off);
        if (t == 0) s_sum = v;
    }
    __syncthreads();
    float inv = 1.0f / (s_sum + 1e-7f);
    if (t < JW) s_a[t] = s_e[t] * inv;
    __syncthreads();

    // Phase 3: v[d] = sum_j a_j * x[base+jlo+j, d]; thread t owns d=t
    const float* xb = x + (size_t)(base + jlo) * DD + t;
    float acc = 0.0f;
    for (int jj = 0; jj < nj; ++jj)
        acc = fmaf(s_a[jj], xb[(size_t)jj * DD], acc);
    out[(size_t)row * DD + t] = acc;
}

extern "C" void kernel_launch(void* const* d_in, const int* in_sizes, int n_in,
                              void* d_out, int out_size, void* d_ws, size_t ws_size,
                              hipStream_t stream) {
    const float* x  = (const float*)d_in[0];
    const float* Wt = (const float*)d_in[1];
    const float* Wx = (const float*)d_in[2];
    const float* bh = (const float*)d_in[3];
    const float* Wa = (const float*)d_in[4];
    const float* ba = (const float*)d_in[5];
    float* out = (float*)d_out;

    float* q = (float*)d_ws;                       // B*L*U floats
    float* kk = q + (size_t)BB * LL * UU;          // B*L*U floats

    qk_kernel<<<(BB * LL) / 8, 256, 0, stream>>>(x, Wt, Wx, bh, q, kk);
    attn_kernel<<<BB * LL, 256, 0, stream>>>(x, q, kk, Wa, ba, out);
}